// Round 22
// baseline (285.193 us; speedup 1.0000x reference)
//
#include <hip/hip_runtime.h>

typedef unsigned short u16;
typedef unsigned int u32;
typedef __attribute__((ext_vector_type(8))) short short8v;   // 8 bf16 MFMA frag
typedef __attribute__((ext_vector_type(4))) float f32x4;
typedef __attribute__((ext_vector_type(2))) float f32x2;
typedef __attribute__((ext_vector_type(4))) unsigned int uint4v;
typedef __attribute__((ext_vector_type(2))) unsigned int uint2v;
typedef __attribute__((ext_vector_type(8))) unsigned short us8;
typedef __attribute__((ext_vector_type(4))) unsigned short us4;

#define B_   4
#define S_   19950
#define C_   256
#define NH   8
#define DH   32
#define BS_  (B_*S_)          // 79800

#define BM 64                 // 64-row M-panels
#define BK 64
#define NPAN 1248             // padded to /8 (tail rows clamped+guarded)

__device__ __forceinline__ float bf2f(u16 u){ u32 x=((u32)u)<<16; float f; __builtin_memcpy(&f,&x,4); return f; }
__device__ __forceinline__ u16 f2bf(float f){ u32 x; __builtin_memcpy(&x,&f,4); x += 0x7fffu + ((x>>16)&1u); return (u16)(x>>16); }
__device__ __forceinline__ u32 cvtpk(float a, float b){ u32 r; asm("v_cvt_pk_bf16_f32 %0, %1, %2" : "=v"(r) : "v"(a), "v"(b)); return r; }
__device__ __forceinline__ f32x2 pkfma(f32x2 a, f32x2 b, f32x2 d){
  asm("v_pk_fma_f32 %0, %1, %2, %0" : "+v"(d) : "v"(a), "v"(b)); return d;
}
__device__ __forceinline__ f32x2 unpk(u32 p){
  uint2v u; u.x = p<<16; u.y = p & 0xffff0000u; return __builtin_bit_cast(f32x2, u);
}

// ====== MFMA GEMM core (round-21 structure) ======
// MODE 0: A=value f32, BN=128 -> v bf16 permuted (b,h,s,dh)
// MODE 3: A=value f32, BN=128 -> v f32  permuted (b,h,s,dh)   [sampler-f32 pipeline]
// MODE 1: A=query f32, BN=96  -> soff/sattn HEAD-MAJOR [(h*4+b)][q][24|12]
// MODE 2: A=tmp bf16,  BN=128 -> out f32.
// vmcnt wait after issuing next-B = NBL outstanding B loads: 6 (MODE1) or 8 (others).
template<int MODE>
__device__ __forceinline__ void gemm_core(int g, u32* smem,
    const void* __restrict__ Aany, const float* __restrict__ Wmain,
    const float* __restrict__ Wattn, const float* __restrict__ bmain,
    const float* __restrict__ battn, void* __restrict__ out0, u16* __restrict__ out1)
{
  constexpr int NX   = (MODE==1) ? 3 : 2;
  constexpr int BROW = (MODE==1) ? 96 : 128;   // B-tile rows (N columns per tile)
  constexpr int NF   = (MODE==1) ? 3 : 4;      // B-frags per wave
  constexpr int NBL  = (MODE==1) ? 6 : 8;      // B staging f32x4 loads per thread
  float* Asf = (float*)smem;                        // f32[64][64] 16KB (A f32 modes)
  u16*  Asb  = (u16*)smem;                          // bf16[64][64] 8KB (MODE2)
  u32*  Bs   = smem + ((MODE==2) ? 2048 : 4096);    // bf16[BROW][64]

  const int tid = threadIdx.x;
  const int x = (g>>3) % NX;
  const int y = ((g>>3)/NX)*8 + (g&7);   // XCD-paired: col-blocks of one A-panel 8 apart -> same XCD
  const int m0 = y * BM;
  const int n0 = x * BROW;
  const int lane = tid & 63;
  const int wid  = tid >> 6;
  const int wm = wid >> 1, wn = wid & 1;
  const int ln15 = lane & 15, ln4 = lane >> 4;

  f32x4 acc[2][NF];
  #pragma unroll
  for (int i=0;i<2;++i){
    #pragma unroll
    for (int j=0;j<NF;++j) acc[i][j] = (f32x4){0.f,0.f,0.f,0.f};
  }

  f32x4 bvv[NBL];
  auto loadB = [&](int k0){
    #pragma unroll
    for (int i=0;i<NBL;++i){
      const int ct = tid + 256*i;
      const int row = ct >> 4, c = ct & 15;
      const int n = n0 + row;
      if constexpr (MODE==1) {
        const float* src = (n < 192) ? (Wmain + (size_t)n*C_) : (Wattn + (size_t)(n-192)*C_);
        bvv[i] = *(const f32x4*)(src + k0 + c*4);
      } else {
        bvv[i] = *(const f32x4*)(Wmain + (size_t)n*C_ + k0 + c*4);
      }
    }
  };

  loadB(0);   // prologue

  #pragma unroll
  for (int kt=0; kt<4; ++kt) {
    const int k0 = kt*BK;
    // ---- A async DMA to LDS first (oldest vmem ops this step) ----
    if constexpr (MODE==2) {
      const u16* Ab = (const u16*)Aany;
      #pragma unroll
      for (int i=0;i<2;++i){
        const int rl = wid*16 + i*8 + (lane>>3);       // row 0..63
        const int rg = min(m0 + rl, BS_-1);
        const int c = lane & 7, cs = c ^ (rl & 7);
        __builtin_amdgcn_global_load_lds(Ab + (size_t)rg*C_ + k0 + cs*8,
            &Asb[(wid*16 + i*8)*64], 16, 0, 0);
      }
    } else {
      const float* Ab = (const float*)Aany;
      #pragma unroll
      for (int i=0;i<4;++i){
        const int rl = wid*16 + i*4 + (lane>>4);       // row 0..63
        const int rg = min(m0 + rl, BS_-1);
        const int c = lane & 15, cs = c ^ (rl & 15);
        __builtin_amdgcn_global_load_lds(Ab + (size_t)rg*C_ + k0 + cs*4,
            &Asf[(wid*16 + i*4)*64], 16, 0, 0);
      }
    }
    __builtin_amdgcn_sched_barrier(0);   // pin: DMA issued before B loads (oldest = DMA)
    // ---- B cvt + swizzled LDS write (waits bvv), then issue next B loads ----
    #pragma unroll
    for (int i=0;i<NBL;++i){
      const int ct = tid + 256*i;
      const int row = ct >> 4, c = ct & 15;
      const u32 p0 = cvtpk(bvv[i].x, bvv[i].y), p1 = cvtpk(bvv[i].z, bvv[i].w);
      const int cc = c >> 1;
      uint2v pk; pk.x = p0; pk.y = p1;
      *(uint2v*)&Bs[row*32 + ((cc ^ (row&7))<<2) + (c&1)*2] = pk;
    }
    if (kt < 3) {
      loadB(k0 + BK);   // newest vmem: stays in flight across barrier + compute
      if constexpr (MODE==1) asm volatile("s_waitcnt vmcnt(6) lgkmcnt(0)" ::: "memory");
      else                   asm volatile("s_waitcnt vmcnt(8) lgkmcnt(0)" ::: "memory");
    } else {
      asm volatile("s_waitcnt vmcnt(0) lgkmcnt(0)" ::: "memory");
    }
    __builtin_amdgcn_s_barrier();
    __builtin_amdgcn_sched_barrier(0);
    // ---- compute: 2 k-sub of 32, 2xNF frags ----
    #pragma unroll
    for (int ks=0; ks<2; ++ks) {
      short8v af[2], bfr[NF];
      #pragma unroll
      for (int mi=0;mi<2;++mi){
        const int row = wm*32 + mi*16 + ln15;
        if constexpr (MODE==2) {
          const int c = ks*4 + ln4;
          af[mi] = *(const short8v*)&Asb[row*64 + ((c ^ (row&7))<<3)];
        } else {
          const int ch = ks*8 + ln4*2;
          const int c1 = ch ^ (row&15), c2 = (ch+1) ^ (row&15);
          const f32x4 lo = *(const f32x4*)&Asf[row*64 + c1*4];
          const f32x4 hi = *(const f32x4*)&Asf[row*64 + c2*4];
          uint4v uu;
          uu.x = cvtpk(lo.x, lo.y); uu.y = cvtpk(lo.z, lo.w);
          uu.z = cvtpk(hi.x, hi.y); uu.w = cvtpk(hi.z, hi.w);
          af[mi] = __builtin_bit_cast(short8v, uu);
        }
      }
      #pragma unroll
      for (int ni=0;ni<NF;++ni){
        const int row = wn*(NF*16) + ni*16 + ln15;
        const int c = ks*4 + ln4;
        bfr[ni] = *(const short8v*)&Bs[row*32 + ((c ^ (row&7))<<2)];
      }
      #pragma unroll
      for (int mi=0;mi<2;++mi){
        #pragma unroll
        for (int ni=0;ni<NF;++ni)
          acc[mi][ni] = __builtin_amdgcn_mfma_f32_16x16x32_bf16(af[mi], bfr[ni], acc[mi][ni], 0, 0, 0);
      }
    }
    __syncthreads();   // barrier-2: full drain
  }

  // ==== epilogue via LDS repack: 16B coalesced stores ====
  if constexpr (MODE==2 || MODE==3) {
    // f32 results, two 32-row passes ([32][132] f32 = 16.9KB); waves wm==p write pass p
    float* Cs = (float*)smem;
    #pragma unroll
    for (int p=0;p<2;++p){
      if (wm == p) {
        #pragma unroll
        for (int mi=0;mi<2;++mi){
          #pragma unroll
          for (int ni=0;ni<4;++ni){
            const int col = wn*64 + ni*16 + ln15;
            const float bv = bmain[n0 + col];
            #pragma unroll
            for (int j=0;j<4;++j){
              const int rl = mi*16 + ln4*4 + j;
              Cs[rl*132 + col] = acc[mi][ni][j] + bv;
            }
          }
        }
      }
      __syncthreads();
      #pragma unroll
      for (int i=0;i<4;++i){
        const int c = i*256 + tid;
        const int row = c >> 5, ch = c & 31;
        const int m = m0 + p*32 + row;
        if (m < BS_) {
          const f32x4 vv = *(const f32x4*)&Cs[row*132 + ch*4];
          if constexpr (MODE==2) {
            *(f32x4*)((float*)out0 + (size_t)m*C_ + n0 + ch*4) = vv;
          } else {
            const int colg = n0 + ch*4;
            const int bq = m / S_, sq = m - bq*S_;
            const int h = colg >> 5, dh0 = colg & 31;
            *(f32x4*)((float*)out0 + ((size_t)(bq*NH+h)*S_ + sq)*DH + dh0) = vv;
          }
        }
      }
      __syncthreads();
    }
  } else if constexpr (MODE==0) {
    u16* Cs = (u16*)smem;
    #pragma unroll
    for (int mi=0;mi<2;++mi){
      #pragma unroll
      for (int ni=0;ni<4;++ni){
        const int col = wn*64 + ni*16 + ln15;
        const float bias = bmain[n0 + col];
        #pragma unroll
        for (int j=0;j<4;++j){
          const int row = wm*32 + mi*16 + ln4*4 + j;
          Cs[row*136 + col] = f2bf(acc[mi][ni][j] + bias);
        }
      }
    }
    __syncthreads();
    #pragma unroll
    for (int i=0;i<4;++i){
      const int c = i*256 + tid;
      const int row = c >> 4, ch = c & 15;
      const int m = m0 + row;
      if (m >= BS_) continue;
      const int colg = n0 + ch*8;
      const int bq = m / S_, sq = m - bq*S_;
      const uint4v vv = *(const uint4v*)&Cs[row*136 + ch*8];
      u16* vout = (u16*)out0;
      const int h = colg >> 5, dh0 = colg & 31;
      *(uint4v*)(vout + ((size_t)(bq*NH+h)*S_ + sq)*DH + dh0) = vv;
    }
  } else {
    // MODE1: BN=96 tile. x<2 -> offsets only; x==2 -> attn only (softmax).
    u16* Cs = (u16*)smem;   // [64][104] u16 = 13.3 KB
    if (x < 2) {
      #pragma unroll
      for (int mi=0;mi<2;++mi){
        #pragma unroll
        for (int ni=0;ni<3;++ni){
          const int col = wn*48 + ni*16 + ln15;
          const float bias = bmain[n0 + col];
          #pragma unroll
          for (int j=0;j<4;++j){
            const int row = wm*32 + mi*16 + ln4*4 + j;
            Cs[row*104 + col] = f2bf(acc[mi][ni][j] + bias);
          }
        }
      }
    } else {
      #pragma unroll
      for (int mi=0;mi<2;++mi){
        #pragma unroll
        for (int ni=0;ni<3;++ni){
          const int col = wn*48 + ni*16 + ln15;
          const float bias = battn[col];
          #pragma unroll
          for (int j=0;j<4;++j){
            const int row = wm*32 + mi*16 + ln4*4 + j;
            const float vv = acc[mi][ni][j] + bias;
            float mx = vv;
            mx = fmaxf(mx, __shfl_xor(mx, 1));
            mx = fmaxf(mx, __shfl_xor(mx, 2));
            const float e = __expf(vv - mx);
            float ssum = e;
            ssum += __shfl_xor(ssum, 1);
            ssum += __shfl_xor(ssum, 2);
            Cs[row*104 + col] = f2bf(e/ssum);
          }
        }
      }
    }
    __syncthreads();
    #pragma unroll
    for (int i=0;i<3;++i){
      const int c = i*256 + tid;                 // 768 chunks of 8 bf16 (64 rows x 12)
      const int row = c / 12, ch = c - row*12;
      const int m = m0 + row;
      if (m >= BS_) continue;
      const int bq = m / S_, sq = m - bq*S_;
      if (x < 2) {
        const int colg = n0 + ch*8;              // < 192, offsets
        const uint4v vv = *(const uint4v*)&Cs[row*104 + ch*8];
        u16* soff = (u16*)out0;
        const int hh = colg / 24, cc = colg - hh*24;
        *(uint4v*)(soff + (((size_t)hh*4 + bq)*S_ + sq)*24 + cc) = vv;
      } else {
        #pragma unroll
        for (int half=0; half<2; ++half){
          const int nl2 = ch*8 + half*4;
          const int hh = nl2 / 12, cc = nl2 - hh*12;
          const uint2v vv = *(const uint2v*)&Cs[row*104 + ch*8 + half*4];
          *(uint2v*)(out1 + (((size_t)hh*4 + bq)*S_ + sq)*12 + cc) = vv;
        }
      }
    }
  }
}

// ---- FUSED projections: blocks [0,2496) = vproj, [2496,6240) = qproj (MODE1, BN=96) ----
__global__ __launch_bounds__(256) void k_projFb(
    const void* __restrict__ value, const float* __restrict__ Wv,
    const float* __restrict__ bv, void* __restrict__ vout,
    const void* __restrict__ query, const float* __restrict__ Wo,
    const float* __restrict__ Wa, const float* __restrict__ bo,
    const float* __restrict__ ba, void* __restrict__ soff, u16* __restrict__ sattn)
{
  __shared__ u32 smem[8192];   // 32 KB
  const int g = blockIdx.x;
  if (g < 2*NPAN) gemm_core<0>(g,          smem, value, Wv, nullptr, bv, nullptr, vout, nullptr);
  else            gemm_core<1>(g - 2*NPAN, smem, query, Wo, Wa,      bo, ba,      soff, sattn);
}

__global__ __launch_bounds__(256) void k_projFf(
    const void* __restrict__ value, const float* __restrict__ Wv,
    const float* __restrict__ bv, void* __restrict__ vout,
    const void* __restrict__ query, const float* __restrict__ Wo,
    const float* __restrict__ Wa, const float* __restrict__ bo,
    const float* __restrict__ ba, void* __restrict__ soff, u16* __restrict__ sattn)
{
  __shared__ u32 smem[8192];   // 32 KB
  const int g = blockIdx.x;
  if (g < 2*NPAN) gemm_core<3>(g,          smem, value, Wv, nullptr, bv, nullptr, vout, nullptr);
  else            gemm_core<1>(g - 2*NPAN, smem, query, Wo, Wa,      bo, ba,      soff, sattn);
}

__global__ __launch_bounds__(256) void k_gemm2F(const void* __restrict__ A,
    const float* __restrict__ W, const float* __restrict__ b, void* __restrict__ o)
{
  __shared__ u32 smem[6144];   // 24 KB
  gemm_core<2>(blockIdx.x, smem, A, W, nullptr, b, nullptr, o, nullptr);
}

#define NCH 312   // ceil(19950/64) chunks of 64 queries

// ==== Sampler v7 (round-21 proven): bf16 v taps ====
__global__ __launch_bounds__(256) void k_sample7(const u16* __restrict__ v,
    const u16* __restrict__ soff, const u16* __restrict__ sattn,
    const float* __restrict__ refp, u16* __restrict__ tmp)
{
  const int g = blockIdx.x;
  const int xcd = g & 7, inner = g >> 3;
  const int unit = inner / NCH;
  const int cidx = inner - unit*NCH;
  const int bh = xcd*4 + unit;
  const int b = bh >> 3, h = bh & 7;
  const int dh0 = (threadIdx.x & 3) * 8;
  const int q = cidx*64 + (threadIdx.x >> 2);
  if (q >= S_) return;
  const size_t r = (size_t)b*S_ + q;
  const float refx = refp[r*2+0], refy = refp[r*2+1];
  const char* vb = (const char*)(v + (size_t)bh * S_ * DH);

  const u16* sop = soff + (((size_t)h*4 + b)*S_ + q)*24;
  const u16* sap = sattn + (((size_t)h*4 + b)*S_ + q)*12;
  us8 so0 = *(const us8*)(sop);
  us8 so1 = *(const us8*)(sop + 8);
  us8 so2 = *(const us8*)(sop + 16);
  us4 sa0 = *(const us4*)(sap);
  us4 sa1 = *(const us4*)(sap + 4);
  us4 sa2 = *(const us4*)(sap + 8);
  u16 soarr[24]; u16 saarr[12];
  #pragma unroll
  for (int i=0;i<8;++i){ soarr[i]=so0[i]; soarr[8+i]=so1[i]; soarr[16+i]=so2[i]; }
  #pragma unroll
  for (int i=0;i<4;++i){ saarr[i]=sa0[i]; saarr[4+i]=sa1[i]; saarr[8+i]=sa2[i]; }

  f32x2 acc0 = (f32x2){0.f,0.f}, acc1 = acc0, acc2 = acc0, acc3 = acc0;
  const int WLs[3]={152,76,38}, HLs[3]={100,50,25}, STs[3]={0,15200,19000};
  const u32 ch2 = (u32)(dh0*2);
  #pragma unroll
  for (int l=0;l<3;++l) {
    const int Wl=WLs[l], Hl=HLs[l];
    const float rxl = refx*(float)Wl - 0.5f;
    const float ryl = refy*(float)Hl - 0.5f;
    const char* vbl = vb + (size_t)STs[l]*DH*2;
    #pragma unroll
    for (int p=0;p<4;++p) {
      const int idx = l*4 + p;
      const float ix = rxl + bf2f(soarr[2*idx+0]);
      const float iy = ryl + bf2f(soarr[2*idx+1]);
      const float aw = bf2f(saarr[idx]);
      const float x0f = floorf(ix), y0f = floorf(iy);
      const float wx1 = ix-x0f, wy1 = iy-y0f;
      const int x0 = (int)x0f, y0 = (int)y0f;
      const int x1 = x0+1, y1 = y0+1;
      const float wx0z = ((u32)x0 < (u32)Wl) ? (1.f-wx1) : 0.f;
      const float wx1z = ((u32)x1 < (u32)Wl) ? wx1 : 0.f;
      const float wy0z = ((u32)y0 < (u32)Hl) ? aw*(1.f-wy1) : 0.f;
      const float wy1z = ((u32)y1 < (u32)Hl) ? aw*wy1 : 0.f;
      const int xi0 = min(max(x0,0),Wl-1), xi1 = min(max(x1,0),Wl-1);
      const int yi0 = min(max(y0,0),Hl-1), yi1 = min(max(y1,0),Hl-1);
      const u32 rb0 = (u32)(yi0*Wl)*64u + ch2;
      const u32 rb1 = (u32)(yi1*Wl)*64u + ch2;
      const uint4v t00 = *(const uint4v*)(vbl + rb0 + (u32)xi0*64u);
      const uint4v t01 = *(const uint4v*)(vbl + rb0 + (u32)xi1*64u);
      const uint4v t10 = *(const uint4v*)(vbl + rb1 + (u32)xi0*64u);
      const uint4v t11 = *(const uint4v*)(vbl + rb1 + (u32)xi1*64u);
      const float w00 = wx0z*wy0z, w01 = wx1z*wy0z;
      const float w10 = wx0z*wy1z, w11 = wx1z*wy1z;
      f32x2 W00 = (f32x2){w00,w00}, W01 = (f32x2){w01,w01};
      f32x2 W10 = (f32x2){w10,w10}, W11 = (f32x2){w11,w11};
      acc0 = pkfma(unpk(t00.x), W00, acc0);
      acc1 = pkfma(unpk(t00.y), W00, acc1);
      acc2 = pkfma(unpk(t00.z), W00, acc2);
      acc3 = pkfma(unpk(t00.w), W00, acc3);
      acc0 = pkfma(unpk(t01.x), W01, acc0);
      acc1 = pkfma(unpk(t01.y), W01, acc1);
      acc2 = pkfma(unpk(t01.z), W01, acc2);
      acc3 = pkfma(unpk(t01.w), W01, acc3);
      acc0 = pkfma(unpk(t10.x), W10, acc0);
      acc1 = pkfma(unpk(t10.y), W10, acc1);
      acc2 = pkfma(unpk(t10.z), W10, acc2);
      acc3 = pkfma(unpk(t10.w), W10, acc3);
      acc0 = pkfma(unpk(t11.x), W11, acc0);
      acc1 = pkfma(unpk(t11.y), W11, acc1);
      acc2 = pkfma(unpk(t11.z), W11, acc2);
      acc3 = pkfma(unpk(t11.w), W11, acc3);
    }
  }
  uint4v o;
  o.x = cvtpk(acc0.x, acc0.y); o.y = cvtpk(acc1.x, acc1.y);
  o.z = cvtpk(acc2.x, acc2.y); o.w = cvtpk(acc3.x, acc3.y);
  *(uint4v*)(tmp + r*C_ + (size_t)h*DH + dh0) = o;
}

// ==== Sampler v8: f32 v taps (no unpk; pkfma direct) ====
__global__ __launch_bounds__(256) void k_sample8(const float* __restrict__ vf,
    const u16* __restrict__ soff, const u16* __restrict__ sattn,
    const float* __restrict__ refp, u16* __restrict__ tmp)
{
  const int g = blockIdx.x;
  const int xcd = g & 7, inner = g >> 3;
  const int unit = inner / NCH;
  const int cidx = inner - unit*NCH;
  const int bh = xcd*4 + unit;
  const int b = bh >> 3, h = bh & 7;
  const int dh0 = (threadIdx.x & 3) * 8;
  const int q = cidx*64 + (threadIdx.x >> 2);
  if (q >= S_) return;
  const size_t r = (size_t)b*S_ + q;
  const float refx = refp[r*2+0], refy = refp[r*2+1];
  const char* vb = (const char*)(vf + (size_t)bh * S_ * DH);

  const u16* sop = soff + (((size_t)h*4 + b)*S_ + q)*24;
  const u16* sap = sattn + (((size_t)h*4 + b)*S_ + q)*12;
  us8 so0 = *(const us8*)(sop);
  us8 so1 = *(const us8*)(sop + 8);
  us8 so2 = *(const us8*)(sop + 16);
  us4 sa0 = *(const us4*)(sap);
  us4 sa1 = *(const us4*)(sap + 4);
  us4 sa2 = *(const us4*)(sap + 8);
  u16 soarr[24]; u16 saarr[12];
  #pragma unroll
  for (int i=0;i<8;++i){ soarr[i]=so0[i]; soarr[8+i]=so1[i]; soarr[16+i]=so2[i]; }
  #pragma unroll
  for (int i=0;i<4;++i){ saarr[i]=sa0[i]; saarr[4+i]=sa1[i]; saarr[8+i]=sa2[i]; }

  f32x2 acc0 = (f32x2){0.f,0.f}, acc1 = acc0, acc2 = acc0, acc3 = acc0;
  const int WLs[3]={152,76,38}, HLs[3]={100,50,25}, STs[3]={0,15200,19000};
  const u32 ch4 = (u32)(dh0*4);
  #pragma unroll
  for (int l=0;l<3;++l) {
    const int Wl=WLs[l], Hl=HLs[l];
    const float rxl = refx*(float)Wl - 0.5f;
    const float ryl = refy*(float)Hl - 0.5f;
    const char* vbl = vb + (size_t)STs[l]*DH*4;
    #pragma unroll
    for (int p=0;p<4;++p) {
      const int idx = l*4 + p;
      const float ix = rxl + bf2f(soarr[2*idx+0]);
      const float iy = ryl + bf2f(soarr[2*idx+1]);
      const float aw = bf2f(saarr[idx]);
      const float x0f = floorf(ix), y0f = floorf(iy);
      const float wx1 = ix-x0f, wy1 = iy-y0f;
      const int x0 = (int)x0f, y0 = (int)y0f;
      const int x1 = x0+1, y1 = y0+1;
      const float wx0z = ((u32)x0 < (u32)Wl) ? (1.f-wx1) : 0.f;
      const float wx1z = ((u32)x1 < (u32)Wl) ? wx1 : 0.f;
      const float wy0z = ((u32)y0 < (u32)Hl) ? aw*(1.f-wy1) : 0.f;
      const float wy1z = ((u32)y1 < (u32)Hl) ? aw*wy1 : 0.f;
      const int xi0 = min(max(x0,0),Wl-1), xi1 = min(max(x1,0),Wl-1);
      const int yi0 = min(max(y0,0),Hl-1), yi1 = min(max(y1,0),Hl-1);
      const u32 rb0 = (u32)(yi0*Wl)*128u + ch4;
      const u32 rb1 = (u32)(yi1*Wl)*128u + ch4;
      const float w00 = wx0z*wy0z, w01 = wx1z*wy0z;
      const float w10 = wx0z*wy1z, w11 = wx1z*wy1z;
      f32x2 W00 = (f32x2){w00,w00}, W01 = (f32x2){w01,w01};
      f32x2 W10 = (f32x2){w10,w10}, W11 = (f32x2){w11,w11};
      const f32x4 a0 = *(const f32x4*)(vbl + rb0 + (u32)xi0*128u);
      const f32x4 b0 = *(const f32x4*)(vbl + rb0 + (u32)xi0*128u + 16);
      const f32x4 a1 = *(const f32x4*)(vbl + rb0 + (u32)xi1*128u);
      const f32x4 b1 = *(const f32x4*)(vbl + rb0 + (u32)xi1*128u + 16);
      const f32x4 a2 = *(const f32x4*)(vbl + rb1 + (u32)xi0*128u);
      const f32x4 b2 = *(const f32x4*)(vbl + rb1 + (u32)xi0*128u + 16);
      const f32x4 a3 = *(const f32x4*)(vbl + rb1 + (u32)xi1*128u);
      const f32x4 b3 = *(const f32x4*)(vbl + rb1 + (u32)xi1*128u + 16);
      acc0 = pkfma((f32x2){a0.x,a0.y}, W00, acc0);
      acc1 = pkfma((f32x2){a0.z,a0.w}, W00, acc1);
      acc2 = pkfma((f32x2){b0.x,b0.y}, W00, acc2);
      acc3 = pkfma((f32x2){b0.z,b0.w}, W00, acc3);
      acc0 = pkfma((f32x2){a1.x,a1.y}, W01, acc0);
      acc1 = pkfma((f32x2){a1.z,a1.w}, W01, acc1);
      acc2 = pkfma((f32x2){b1.x,b1.y}, W01, acc2);
      acc3 = pkfma((f32x2){b1.z,b1.w}, W01, acc3);
      acc0 = pkfma((f32x2){a2.x,a2.y}, W10, acc0);
      acc1 = pkfma((f32x2){a2.z,a2.w}, W10, acc1);
      acc2 = pkfma((f32x2){b2.x,b2.y}, W10, acc2);
      acc3 = pkfma((f32x2){b2.z,b2.w}, W10, acc3);
      acc0 = pkfma((f32x2){a3.x,a3.y}, W11, acc0);
      acc1 = pkfma((f32x2){a3.z,a3.w}, W11, acc1);
      acc2 = pkfma((f32x2){b3.x,b3.y}, W11, acc2);
      acc3 = pkfma((f32x2){b3.z,b3.w}, W11, acc3);
    }
  }
  uint4v o;
  o.x = cvtpk(acc0.x, acc0.y); o.y = cvtpk(acc1.x, acc1.y);
  o.z = cvtpk(acc2.x, acc2.y); o.w = cvtpk(acc3.x, acc3.y);
  *(uint4v*)(tmp + r*C_ + (size_t)h*DH + dh0) = o;
}

extern "C" void kernel_launch(void* const* d_in, const int* in_sizes, int n_in,
                              void* d_out, int out_size, void* d_ws, size_t ws_size,
                              hipStream_t stream) {
  (void)in_sizes; (void)n_in; (void)out_size;
  const float* query = (const float*)d_in[0];
  const float* value = (const float*)d_in[1];
  const float* refp  = (const float*)d_in[4];
  const float* W_off = (const float*)d_in[5];
  const float* b_off = (const float*)d_in[6];
  const float* W_attn= (const float*)d_in[7];
  const float* b_attn= (const float*)d_in[8];
  const float* W_val = (const float*)d_in[9];
  const float* b_val = (const float*)d_in[10];
  const float* W_out = (const float*)d_in[11];
  const float* b_out = (const float*)d_in[12];
  float* out = (float*)d_out;

  char* ws = (char*)d_ws;
  constexpr size_t SOFF_BYTES = (size_t)BS_*24*NH*2;  // 30.6 MB head-major
  constexpr size_t SATTN_BYTES= (size_t)BS_*12*NH*2;  // 15.3 MB head-major
  constexpr size_t TMP_BYTES  = (size_t)BS_*C_*2;     // 40.9 MB
  constexpr size_t VB_BYTES   = (size_t)BS_*C_*2;     // 40.9 MB (bf16 v)
  constexpr size_t VF_BYTES   = (size_t)BS_*C_*4;     // 81.7 MB (f32 v)
  const bool useF32 = ws_size >= (VF_BYTES + SOFF_BYTES + SATTN_BYTES + TMP_BYTES);
  const size_t vbytes = useF32 ? VF_BYTES : VB_BYTES;

  void* v     = (void*)(ws);
  u16* soff   = (u16*)(ws + vbytes);
  u16* sattn  = (u16*)(ws + vbytes + SOFF_BYTES);
  u16* tmp    = (u16*)(ws + vbytes + SOFF_BYTES + SATTN_BYTES);

  dim3 blk(256);
  if (useF32) {
    hipLaunchKernelGGL(k_projFf, dim3(5*NPAN), blk, 0, stream,
                       (const void*)value, W_val, b_val, v,
                       (const void*)query, W_off, W_attn, b_off, b_attn,
                       (void*)soff, sattn);
    hipLaunchKernelGGL(k_sample8, dim3(8*4*NCH), blk, 0, stream,
                       (const float*)v, soff, sattn, refp, tmp);
  } else {
    hipLaunchKernelGGL(k_projFb, dim3(5*NPAN), blk, 0, stream,
                       (const void*)value, W_val, b_val, v,
                       (const void*)query, W_off, W_attn, b_off, b_attn,
                       (void*)soff, sattn);
    hipLaunchKernelGGL(k_sample7, dim3(8*4*NCH), blk, 0, stream,
                       (const u16*)v, soff, sattn, refp, tmp);
  }
  hipLaunchKernelGGL(k_gemm2F, dim3(2*NPAN), blk, 0, stream,
                     (const void*)tmp, W_out, b_out, (void*)out);
}

// Round 24
// 225.250 us; speedup vs baseline: 1.2661x; 1.2661x over previous
//
#include <hip/hip_runtime.h>

typedef unsigned short u16;
typedef unsigned int u32;
typedef __attribute__((ext_vector_type(8))) short short8v;   // 8 bf16 MFMA frag
typedef __attribute__((ext_vector_type(4))) float f32x4;
typedef __attribute__((ext_vector_type(2))) float f32x2;
typedef __attribute__((ext_vector_type(4))) unsigned int uint4v;
typedef __attribute__((ext_vector_type(2))) unsigned int uint2v;
typedef __attribute__((ext_vector_type(8))) unsigned short us8;
typedef __attribute__((ext_vector_type(4))) unsigned short us4;

#define B_   4
#define S_   19950
#define C_   256
#define NH   8
#define DH   32
#define BS_  (B_*S_)          // 79800

#define BM 64                 // 64-row M-panels
#define BK 64
#define NPAN 1248             // padded to /8 (tail rows clamped+guarded)

__device__ __forceinline__ float bf2f(u16 u){ u32 x=((u32)u)<<16; float f; __builtin_memcpy(&f,&x,4); return f; }
__device__ __forceinline__ u16 f2bf(float f){ u32 x; __builtin_memcpy(&x,&f,4); x += 0x7fffu + ((x>>16)&1u); return (u16)(x>>16); }
__device__ __forceinline__ u32 cvtpk(float a, float b){ u32 r; asm("v_cvt_pk_bf16_f32 %0, %1, %2" : "=v"(r) : "v"(a), "v"(b)); return r; }
__device__ __forceinline__ f32x2 pkfma(f32x2 a, f32x2 b, f32x2 d){
  asm("v_pk_fma_f32 %0, %1, %2, %0" : "+v"(d) : "v"(a), "v"(b)); return d;
}
__device__ __forceinline__ f32x2 unpk(u32 p){
  uint2v u; u.x = p<<16; u.y = p & 0xffff0000u; return __builtin_bit_cast(f32x2, u);
}

// ====== MFMA GEMM core (round-21 PROVEN 226us config) ======
// MODE 0: A=value f32, BN=128 -> v bf16 permuted (b,h,s,dh)
// MODE 1: A=query f32, BN=96  -> soff/sattn HEAD-MAJOR [(h*4+b)][q][24|12]
// MODE 2: A=tmp bf16,  BN=128 -> out f32.
// vmcnt wait after issuing next-B = NBL outstanding B loads: 6 (MODE1) or 8 (others).
template<int MODE>
__device__ __forceinline__ void gemm_core(int g, u32* smem,
    const void* __restrict__ Aany, const float* __restrict__ Wmain,
    const float* __restrict__ Wattn, const float* __restrict__ bmain,
    const float* __restrict__ battn, void* __restrict__ out0, u16* __restrict__ out1)
{
  constexpr int NX   = (MODE==1) ? 3 : 2;
  constexpr int BROW = (MODE==1) ? 96 : 128;   // B-tile rows (N columns per tile)
  constexpr int NF   = (MODE==1) ? 3 : 4;      // B-frags per wave
  constexpr int NBL  = (MODE==1) ? 6 : 8;      // B staging f32x4 loads per thread
  float* Asf = (float*)smem;                        // MODE0/1: f32[64][64] 16KB
  u16*  Asb  = (u16*)smem;                          // MODE2:   bf16[64][64] 8KB
  u32*  Bs   = smem + ((MODE==2) ? 2048 : 4096);    // bf16[BROW][64]

  const int tid = threadIdx.x;
  const int x = (g>>3) % NX;
  const int y = ((g>>3)/NX)*8 + (g&7);   // XCD-paired: col-blocks of one A-panel 8 apart -> same XCD
  const int m0 = y * BM;
  const int n0 = x * BROW;
  const int lane = tid & 63;
  const int wid  = tid >> 6;
  const int wm = wid >> 1, wn = wid & 1;
  const int ln15 = lane & 15, ln4 = lane >> 4;

  f32x4 acc[2][NF];
  #pragma unroll
  for (int i=0;i<2;++i){
    #pragma unroll
    for (int j=0;j<NF;++j) acc[i][j] = (f32x4){0.f,0.f,0.f,0.f};
  }

  f32x4 bvv[NBL];
  auto loadB = [&](int k0){
    #pragma unroll
    for (int i=0;i<NBL;++i){
      const int ct = tid + 256*i;
      const int row = ct >> 4, c = ct & 15;
      const int n = n0 + row;
      if constexpr (MODE==1) {
        const float* src = (n < 192) ? (Wmain + (size_t)n*C_) : (Wattn + (size_t)(n-192)*C_);
        bvv[i] = *(const f32x4*)(src + k0 + c*4);
      } else {
        bvv[i] = *(const f32x4*)(Wmain + (size_t)n*C_ + k0 + c*4);
      }
    }
  };

  loadB(0);   // prologue

  #pragma unroll
  for (int kt=0; kt<4; ++kt) {
    const int k0 = kt*BK;
    // ---- A async DMA to LDS first (oldest vmem ops this step) ----
    if constexpr (MODE==2) {
      const u16* Ab = (const u16*)Aany;
      #pragma unroll
      for (int i=0;i<2;++i){
        const int rl = wid*16 + i*8 + (lane>>3);       // row 0..63
        const int rg = min(m0 + rl, BS_-1);
        const int c = lane & 7, cs = c ^ (rl & 7);
        __builtin_amdgcn_global_load_lds(Ab + (size_t)rg*C_ + k0 + cs*8,
            &Asb[(wid*16 + i*8)*64], 16, 0, 0);
      }
    } else {
      const float* Ab = (const float*)Aany;
      #pragma unroll
      for (int i=0;i<4;++i){
        const int rl = wid*16 + i*4 + (lane>>4);       // row 0..63
        const int rg = min(m0 + rl, BS_-1);
        const int c = lane & 15, cs = c ^ (rl & 15);
        __builtin_amdgcn_global_load_lds(Ab + (size_t)rg*C_ + k0 + cs*4,
            &Asf[(wid*16 + i*4)*64], 16, 0, 0);
      }
    }
    __builtin_amdgcn_sched_barrier(0);   // pin: DMA issued before B loads (oldest = DMA)
    // ---- B cvt + swizzled LDS write (waits bvv), then issue next B loads ----
    #pragma unroll
    for (int i=0;i<NBL;++i){
      const int ct = tid + 256*i;
      const int row = ct >> 4, c = ct & 15;
      const u32 p0 = cvtpk(bvv[i].x, bvv[i].y), p1 = cvtpk(bvv[i].z, bvv[i].w);
      const int cc = c >> 1;
      uint2v pk; pk.x = p0; pk.y = p1;
      *(uint2v*)&Bs[row*32 + ((cc ^ (row&7))<<2) + (c&1)*2] = pk;
    }
    if (kt < 3) {
      loadB(k0 + BK);   // newest vmem: stays in flight across barrier + compute
      if constexpr (MODE==1) asm volatile("s_waitcnt vmcnt(6) lgkmcnt(0)" ::: "memory");
      else                   asm volatile("s_waitcnt vmcnt(8) lgkmcnt(0)" ::: "memory");
    } else {
      asm volatile("s_waitcnt vmcnt(0) lgkmcnt(0)" ::: "memory");
    }
    __builtin_amdgcn_s_barrier();
    __builtin_amdgcn_sched_barrier(0);
    // ---- compute: 2 k-sub of 32, 2xNF frags ----
    #pragma unroll
    for (int ks=0; ks<2; ++ks) {
      short8v af[2], bfr[NF];
      #pragma unroll
      for (int mi=0;mi<2;++mi){
        const int row = wm*32 + mi*16 + ln15;
        if constexpr (MODE==2) {
          const int c = ks*4 + ln4;
          af[mi] = *(const short8v*)&Asb[row*64 + ((c ^ (row&7))<<3)];
        } else {
          const int ch = ks*8 + ln4*2;
          const int c1 = ch ^ (row&15), c2 = (ch+1) ^ (row&15);
          const f32x4 lo = *(const f32x4*)&Asf[row*64 + c1*4];
          const f32x4 hi = *(const f32x4*)&Asf[row*64 + c2*4];
          uint4v uu;
          uu.x = cvtpk(lo.x, lo.y); uu.y = cvtpk(lo.z, lo.w);
          uu.z = cvtpk(hi.x, hi.y); uu.w = cvtpk(hi.z, hi.w);
          af[mi] = __builtin_bit_cast(short8v, uu);
        }
      }
      #pragma unroll
      for (int ni=0;ni<NF;++ni){
        const int row = wn*(NF*16) + ni*16 + ln15;
        const int c = ks*4 + ln4;
        bfr[ni] = *(const short8v*)&Bs[row*32 + ((c ^ (row&7))<<2)];
      }
      #pragma unroll
      for (int mi=0;mi<2;++mi){
        #pragma unroll
        for (int ni=0;ni<NF;++ni)
          acc[mi][ni] = __builtin_amdgcn_mfma_f32_16x16x32_bf16(af[mi], bfr[ni], acc[mi][ni], 0, 0, 0);
      }
    }
    __syncthreads();   // barrier-2: full drain
  }

  // ==== epilogue via LDS repack: 16B coalesced stores ====
  if constexpr (MODE==2) {
    float* Cs = (float*)smem;
    float* outp = (float*)out0;
    #pragma unroll
    for (int p=0;p<2;++p){
      if (wm == p) {
        #pragma unroll
        for (int mi=0;mi<2;++mi){
          #pragma unroll
          for (int ni=0;ni<4;++ni){
            const int col = wn*64 + ni*16 + ln15;
            const float bv = bmain[n0 + col];
            #pragma unroll
            for (int j=0;j<4;++j){
              const int rl = mi*16 + ln4*4 + j;
              Cs[rl*132 + col] = acc[mi][ni][j] + bv;
            }
          }
        }
      }
      __syncthreads();
      #pragma unroll
      for (int i=0;i<4;++i){
        const int c = i*256 + tid;
        const int row = c >> 5, ch = c & 31;
        const int m = m0 + p*32 + row;
        if (m < BS_) {
          const f32x4 vv = *(const f32x4*)&Cs[row*132 + ch*4];
          *(f32x4*)(outp + (size_t)m*C_ + n0 + ch*4) = vv;
        }
      }
      __syncthreads();
    }
  } else if constexpr (MODE==0) {
    u16* Cs = (u16*)smem;
    #pragma unroll
    for (int mi=0;mi<2;++mi){
      #pragma unroll
      for (int ni=0;ni<4;++ni){
        const int col = wn*64 + ni*16 + ln15;
        const float bias = bmain[n0 + col];
        #pragma unroll
        for (int j=0;j<4;++j){
          const int row = wm*32 + mi*16 + ln4*4 + j;
          Cs[row*136 + col] = f2bf(acc[mi][ni][j] + bias);
        }
      }
    }
    __syncthreads();
    #pragma unroll
    for (int i=0;i<4;++i){
      const int c = i*256 + tid;
      const int row = c >> 4, ch = c & 15;
      const int m = m0 + row;
      if (m >= BS_) continue;
      const int colg = n0 + ch*8;
      const int bq = m / S_, sq = m - bq*S_;
      const uint4v vv = *(const uint4v*)&Cs[row*136 + ch*8];
      u16* vout = (u16*)out0;
      const int h = colg >> 5, dh0 = colg & 31;
      *(uint4v*)(vout + ((size_t)(bq*NH+h)*S_ + sq)*DH + dh0) = vv;
    }
  } else {
    // MODE1: BN=96 tile. x<2 -> offsets only; x==2 -> attn only (softmax).
    u16* Cs = (u16*)smem;   // [64][104] u16 = 13.3 KB
    if (x < 2) {
      #pragma unroll
      for (int mi=0;mi<2;++mi){
        #pragma unroll
        for (int ni=0;ni<3;++ni){
          const int col = wn*48 + ni*16 + ln15;
          const float bias = bmain[n0 + col];
          #pragma unroll
          for (int j=0;j<4;++j){
            const int row = wm*32 + mi*16 + ln4*4 + j;
            Cs[row*104 + col] = f2bf(acc[mi][ni][j] + bias);
          }
        }
      }
    } else {
      #pragma unroll
      for (int mi=0;mi<2;++mi){
        #pragma unroll
        for (int ni=0;ni<3;++ni){
          const int col = wn*48 + ni*16 + ln15;
          const float bias = battn[col];
          #pragma unroll
          for (int j=0;j<4;++j){
            const int row = wm*32 + mi*16 + ln4*4 + j;
            const float vv = acc[mi][ni][j] + bias;
            float mx = vv;
            mx = fmaxf(mx, __shfl_xor(mx, 1));
            mx = fmaxf(mx, __shfl_xor(mx, 2));
            const float e = __expf(vv - mx);
            float ssum = e;
            ssum += __shfl_xor(ssum, 1);
            ssum += __shfl_xor(ssum, 2);
            Cs[row*104 + col] = f2bf(e/ssum);
          }
        }
      }
    }
    __syncthreads();
    #pragma unroll
    for (int i=0;i<3;++i){
      const int c = i*256 + tid;                 // 768 chunks of 8 bf16 (64 rows x 12)
      const int row = c / 12, ch = c - row*12;
      const int m = m0 + row;
      if (m >= BS_) continue;
      const int bq = m / S_, sq = m - bq*S_;
      if (x < 2) {
        const int colg = n0 + ch*8;              // < 192, offsets
        const uint4v vv = *(const uint4v*)&Cs[row*104 + ch*8];
        u16* soff = (u16*)out0;
        const int hh = colg / 24, cc = colg - hh*24;
        *(uint4v*)(soff + (((size_t)hh*4 + bq)*S_ + sq)*24 + cc) = vv;
      } else {
        #pragma unroll
        for (int half=0; half<2; ++half){
          const int nl2 = ch*8 + half*4;
          const int hh = nl2 / 12, cc = nl2 - hh*12;
          const uint2v vv = *(const uint2v*)&Cs[row*104 + ch*8 + half*4];
          *(uint2v*)(out1 + (((size_t)hh*4 + bq)*S_ + sq)*12 + cc) = vv;
        }
      }
    }
  }
}

// ---- FUSED projections: blocks [0,2496) = vproj (MODE0), [2496,6240) = qproj (MODE1, BN=96) ----
__global__ __launch_bounds__(256) void k_projF(
    const void* __restrict__ value, const float* __restrict__ Wv,
    const float* __restrict__ bv, void* __restrict__ vout,
    const void* __restrict__ query, const float* __restrict__ Wo,
    const float* __restrict__ Wa, const float* __restrict__ bo,
    const float* __restrict__ ba, void* __restrict__ soff, u16* __restrict__ sattn)
{
  __shared__ u32 smem[8192];   // 32 KB
  const int g = blockIdx.x;
  if (g < 2*NPAN) gemm_core<0>(g,          smem, value, Wv, nullptr, bv, nullptr, vout, nullptr);
  else            gemm_core<1>(g - 2*NPAN, smem, query, Wo, Wa,      bo, ba,      soff, sattn);
}

__global__ __launch_bounds__(256) void k_gemm2F(const void* __restrict__ A,
    const float* __restrict__ W, const float* __restrict__ b, void* __restrict__ o)
{
  __shared__ u32 smem[6144];   // 24 KB
  gemm_core<2>(blockIdx.x, smem, A, W, nullptr, b, nullptr, o, nullptr);
}

// ==== Sampler v7 (round-21 proven): head-major dense records + v4 arithmetic ====
#define NCH 312   // ceil(19950/64) chunks of 64 queries

__global__ __launch_bounds__(256) void k_sample7(const u16* __restrict__ v,
    const u16* __restrict__ soff, const u16* __restrict__ sattn,
    const float* __restrict__ refp, u16* __restrict__ tmp)
{
  const int g = blockIdx.x;
  const int xcd = g & 7, inner = g >> 3;      // inner in [0, 4*NCH)
  const int unit = inner / NCH;               // 0..3
  const int cidx = inner - unit*NCH;
  const int bh = xcd*4 + unit;                // 4 (b,h)-slices per XCD for L2 locality
  const int b = bh >> 3, h = bh & 7;
  const int dh0 = (threadIdx.x & 3) * 8;
  const int q = cidx*64 + (threadIdx.x >> 2);
  if (q >= S_) return;
  const size_t r = (size_t)b*S_ + q;
  const float refx = refp[r*2+0], refy = refp[r*2+1];
  const char* vb = (const char*)(v + (size_t)bh * S_ * DH);

  // head-major dense records: 48B offsets + 24B weights per (h,b,q)
  const u16* sop = soff + (((size_t)h*4 + b)*S_ + q)*24;
  const u16* sap = sattn + (((size_t)h*4 + b)*S_ + q)*12;
  us8 so0 = *(const us8*)(sop);
  us8 so1 = *(const us8*)(sop + 8);
  us8 so2 = *(const us8*)(sop + 16);
  us4 sa0 = *(const us4*)(sap);
  us4 sa1 = *(const us4*)(sap + 4);
  us4 sa2 = *(const us4*)(sap + 8);
  u16 soarr[24]; u16 saarr[12];
  #pragma unroll
  for (int i=0;i<8;++i){ soarr[i]=so0[i]; soarr[8+i]=so1[i]; soarr[16+i]=so2[i]; }
  #pragma unroll
  for (int i=0;i<4;++i){ saarr[i]=sa0[i]; saarr[4+i]=sa1[i]; saarr[8+i]=sa2[i]; }

  f32x2 acc0 = (f32x2){0.f,0.f}, acc1 = acc0, acc2 = acc0, acc3 = acc0;
  const int WLs[3]={152,76,38}, HLs[3]={100,50,25}, STs[3]={0,15200,19000};
  const u32 ch2 = (u32)(dh0*2);
  #pragma unroll
  for (int l=0;l<3;++l) {
    const int Wl=WLs[l], Hl=HLs[l];
    const float rxl = refx*(float)Wl - 0.5f;   // ix = ref*W + off - 0.5 (normalizer folded)
    const float ryl = refy*(float)Hl - 0.5f;
    const char* vbl = vb + (size_t)STs[l]*DH*2;
    #pragma unroll
    for (int p=0;p<4;++p) {
      const int idx = l*4 + p;
      const float ix = rxl + bf2f(soarr[2*idx+0]);
      const float iy = ryl + bf2f(soarr[2*idx+1]);
      const float aw = bf2f(saarr[idx]);
      const float x0f = floorf(ix), y0f = floorf(iy);
      const float wx1 = ix-x0f, wy1 = iy-y0f;
      const int x0 = (int)x0f, y0 = (int)y0f;
      const int x1 = x0+1, y1 = y0+1;
      // separable zeroed weights (validity folded; aw folded into y factors)
      const float wx0z = ((u32)x0 < (u32)Wl) ? (1.f-wx1) : 0.f;
      const float wx1z = ((u32)x1 < (u32)Wl) ? wx1 : 0.f;
      const float wy0z = ((u32)y0 < (u32)Hl) ? aw*(1.f-wy1) : 0.f;
      const float wy1z = ((u32)y1 < (u32)Hl) ? aw*wy1 : 0.f;
      const int xi0 = min(max(x0,0),Wl-1), xi1 = min(max(x1,0),Wl-1);
      const int yi0 = min(max(y0,0),Hl-1), yi1 = min(max(y1,0),Hl-1);
      const u32 rb0 = (u32)(yi0*Wl)*64u + ch2;
      const u32 rb1 = (u32)(yi1*Wl)*64u + ch2;
      const uint4v t00 = *(const uint4v*)(vbl + rb0 + (u32)xi0*64u);
      const uint4v t01 = *(const uint4v*)(vbl + rb0 + (u32)xi1*64u);
      const uint4v t10 = *(const uint4v*)(vbl + rb1 + (u32)xi0*64u);
      const uint4v t11 = *(const uint4v*)(vbl + rb1 + (u32)xi1*64u);
      const float w00 = wx0z*wy0z, w01 = wx1z*wy0z;
      const float w10 = wx0z*wy1z, w11 = wx1z*wy1z;
      f32x2 W00 = (f32x2){w00,w00}, W01 = (f32x2){w01,w01};
      f32x2 W10 = (f32x2){w10,w10}, W11 = (f32x2){w11,w11};
      acc0 = pkfma(unpk(t00.x), W00, acc0);
      acc1 = pkfma(unpk(t00.y), W00, acc1);
      acc2 = pkfma(unpk(t00.z), W00, acc2);
      acc3 = pkfma(unpk(t00.w), W00, acc3);
      acc0 = pkfma(unpk(t01.x), W01, acc0);
      acc1 = pkfma(unpk(t01.y), W01, acc1);
      acc2 = pkfma(unpk(t01.z), W01, acc2);
      acc3 = pkfma(unpk(t01.w), W01, acc3);
      acc0 = pkfma(unpk(t10.x), W10, acc0);
      acc1 = pkfma(unpk(t10.y), W10, acc1);
      acc2 = pkfma(unpk(t10.z), W10, acc2);
      acc3 = pkfma(unpk(t10.w), W10, acc3);
      acc0 = pkfma(unpk(t11.x), W11, acc0);
      acc1 = pkfma(unpk(t11.y), W11, acc1);
      acc2 = pkfma(unpk(t11.z), W11, acc2);
      acc3 = pkfma(unpk(t11.w), W11, acc3);
    }
  }
  uint4v o;
  o.x = cvtpk(acc0.x, acc0.y); o.y = cvtpk(acc1.x, acc1.y);
  o.z = cvtpk(acc2.x, acc2.y); o.w = cvtpk(acc3.x, acc3.y);
  *(uint4v*)(tmp + r*C_ + (size_t)h*DH + dh0) = o;
}

extern "C" void kernel_launch(void* const* d_in, const int* in_sizes, int n_in,
                              void* d_out, int out_size, void* d_ws, size_t ws_size,
                              hipStream_t stream) {
  (void)in_sizes; (void)n_in; (void)out_size; (void)ws_size;
  const float* query = (const float*)d_in[0];
  const float* value = (const float*)d_in[1];
  const float* refp  = (const float*)d_in[4];
  const float* W_off = (const float*)d_in[5];
  const float* b_off = (const float*)d_in[6];
  const float* W_attn= (const float*)d_in[7];
  const float* b_attn= (const float*)d_in[8];
  const float* W_val = (const float*)d_in[9];
  const float* b_val = (const float*)d_in[10];
  const float* W_out = (const float*)d_in[11];
  const float* b_out = (const float*)d_in[12];
  float* out = (float*)d_out;

  char* ws = (char*)d_ws;
  constexpr size_t V_BYTES    = (size_t)BS_*C_*2;     // 40.9 MB: v bf16 (b,h,s,dh)
  constexpr size_t SOFF_BYTES = (size_t)BS_*24*NH*2;  // 30.6 MB head-major
  constexpr size_t SATTN_BYTES= (size_t)BS_*12*NH*2;  // 15.3 MB head-major
  u16* v     = (u16*)(ws);
  u16* soff  = (u16*)(ws + V_BYTES);
  u16* sattn = (u16*)(ws + V_BYTES + SOFF_BYTES);
  u16* tmp   = (u16*)(ws + V_BYTES + SOFF_BYTES + SATTN_BYTES);

  dim3 blk(256);
  hipLaunchKernelGGL(k_projF, dim3(5*NPAN), blk, 0, stream,
                     (const void*)value, W_val, b_val, (void*)v,
                     (const void*)query, W_off, W_attn, b_off, b_attn,
                     (void*)soff, sattn);
  hipLaunchKernelGGL(k_sample7, dim3(8*4*NCH), blk, 0, stream, v, soff, sattn, refp, tmp);
  hipLaunchKernelGGL(k_gemm2F, dim3(2*NPAN), blk, 0, stream,
                     (const void*)tmp, W_out, b_out, (void*)out);
}